// Round 1
// 2542.365 us; speedup vs baseline: 1.0444x; 1.0444x over previous
//
#include <hip/hip_runtime.h>

// ---------------------------------------------------------------------------
// GaussianGradientLSTMPolicy on MI355X
//   A0: fp32 -> bf16 converts (x, weights), bias fusions
//   A2: shared = leaky_relu(x @ W1^T + b1)                  [131072 x 256]
//   A3: ig     = shared @ W_ih^T + (b_ih + b_hh)  (permuted)[131072 x 1024]
//   B : persistent-register LSTM scan, block pairs exchange h halves
//       R4: same-XCD pairing + dual-path exchange
//         - pair (g, g+16): same XCD under round-robin dispatch (bid % 8)
//         - producer publishes tagged words twice: plain store (visible in
//           the shared per-XCD L2, ~100-200cy) + sc0/sc1 store (write-through
//           LLC, correct for ANY placement)
//         - consumer alternates sc0 poll (L2 fast path) with sc0/sc1 poll
//           (LLC liveness path) -> no placement assumption for correctness
//         - Xbuf transposed to [g][parity][jcol][m]: both publish and poll
//           are single dwordx4 ops
//         - raw barriers (lgkmcnt-only) inside the loop: the poll's own
//           vmcnt(0) provides the ig[t]-load vs hid[t]-store alias drain,
//           so barriers no longer serialize on the hid/pre store queue
//   C : means = tanh(pre@Wm^T+bm), stds = softplus(pre@Ws^T+bs)+eps
// Aliasing:
//   - x_bf16 lives in d_out[0 .. 32MiB) (means+stds region), consumed by A2
//   - ig (bf16) lives in the d_out hidden_outputs region with a PERMUTED
//     layout such that the bytes block (g,ph) reads as ig[t] are exactly the
//     bytes it writes as hid[t]:
//       idx_u16(t,b,q,ph,jl) = t*262144 + (q>>1)*131072 + b*512
//                              + ph*256 + (q&1)*128 + jl
//     Per-block aliasing only; within a block the poll's vmcnt(0) (t>=1) or
//     the pre-loop __syncthreads (t=0) orders all ig[t] loads before any
//     hid[t] store.
// ---------------------------------------------------------------------------

typedef __attribute__((ext_vector_type(8))) short short8;
typedef __attribute__((ext_vector_type(4))) float f32x4;
typedef __attribute__((ext_vector_type(4))) unsigned short u16x4;
typedef __attribute__((ext_vector_type(4))) unsigned int u32x4;
typedef unsigned short u16;
typedef unsigned int   u32;

// ws layout (bytes)
constexpr size_t OFF_SH   = 0;                      // shared bf16   67108864
constexpr size_t OFF_PRE  = 67108864;               // pre bf16      67108864
constexpr size_t OFF_W1   = 134217728;              // W1 bf16          65536
constexpr size_t OFF_WIH  = OFF_W1   + 65536;       // W_ih bf16       524288
constexpr size_t OFF_WHH  = OFF_WIH  + 524288;      // W_hh bf16       524288
constexpr size_t OFF_WCAT = OFF_WHH  + 524288;      // [Wm;Ws] bf16     32768
constexpr size_t OFF_BIG  = OFF_WCAT + 32768;       // b_ih+b_hh f32     4096
constexpr size_t OFF_BCAT = OFF_BIG  + 4096;        // [bm;bs] f32        256
constexpr size_t OFF_X    = OFF_BCAT + 256;         // h2 exchange     524288
// total ~136 MB

__device__ __forceinline__ u16 f2bf(float f) {
  union { float f; u32 u; } v; v.f = f;
  u32 u = v.u;
  return (u16)((u + 0x7fffu + ((u >> 16) & 1u)) >> 16);   // RNE
}
__device__ __forceinline__ float bf2f(u16 h) {
  union { u32 u; float f; } v; v.u = ((u32)h) << 16; return v.f;
}
__device__ __forceinline__ float fsigmoid(float x) {
  return 1.0f / (1.0f + __expf(-x));
}
__device__ __forceinline__ float ftanh(float x) {
  return 1.0f - 2.0f / (__expf(2.0f * x) + 1.0f);
}

// ---------------------------------------------------------------- converts
__global__ void k_conv_x(const float* __restrict__ x, u16* __restrict__ o) {
  const size_t stride = (size_t)gridDim.x * blockDim.x;
  for (size_t i = (size_t)blockIdx.x * blockDim.x + threadIdx.x;
       i < 16777216 / 4; i += stride) {
    f32x4 v = ((const f32x4*)x)[i];
    u16x4 r;
    r[0] = f2bf(v[0]); r[1] = f2bf(v[1]); r[2] = f2bf(v[2]); r[3] = f2bf(v[3]);
    ((u16x4*)o)[i] = r;
  }
}

__global__ void k_small(const float* __restrict__ W1, const float* __restrict__ Wih,
                        const float* __restrict__ Whh, const float* __restrict__ Wm,
                        const float* __restrict__ Ws,  const float* __restrict__ bih,
                        const float* __restrict__ bhh, const float* __restrict__ bm,
                        const float* __restrict__ bs,
                        u16* __restrict__ W1b, u16* __restrict__ Wihb,
                        u16* __restrict__ Whhb, u16* __restrict__ Wcatb,
                        float* __restrict__ bigv, float* __restrict__ bcatv) {
  const int stride = gridDim.x * blockDim.x;
  const int i0 = blockIdx.x * blockDim.x + threadIdx.x;
  for (int i = i0; i < 32768;  i += stride) W1b[i]  = f2bf(W1[i]);
  for (int i = i0; i < 262144; i += stride) Wihb[i] = f2bf(Wih[i]);
  for (int i = i0; i < 262144; i += stride) Whhb[i] = f2bf(Whh[i]);
  for (int i = i0; i < 8192;   i += stride) Wcatb[i]        = f2bf(Wm[i]);
  for (int i = i0; i < 8192;   i += stride) Wcatb[8192 + i] = f2bf(Ws[i]);
  for (int i = i0; i < 1024;   i += stride) bigv[i] = bih[i] + bhh[i];
  for (int i = i0; i < 32;     i += stride) bcatv[i]      = bm[i];
  for (int i = i0; i < 32;     i += stride) bcatv[32 + i] = bs[i];
}

// ------------------------------------------------------------ generic GEMM
// C[M,N] = epi(A[M,K] @ W[N,K]^T + bias), bf16 in, fp32 acc.
// EPI 0: leaky_relu -> bf16 out (ld = N)
// EPI 1: bf16 out, permuted so scan-block (g,ph)'s ig[t] bytes == its hid[t]
// EPI 2: heads: n<32 -> tanh -> means(f32); n>=32 -> softplus+eps -> stds
template <int K, int EPI>
__global__ __launch_bounds__(256) void gemm_bt(const u16* __restrict__ A,
                                               const u16* __restrict__ W,
                                               const float* __restrict__ bias,
                                               void* __restrict__ outp, int N) {
  __shared__ __align__(16) u16 As[64 * 40];   // +8 pad: 2-way banks only
  __shared__ __align__(16) u16 Wt[64 * 40];
  const int tid  = threadIdx.x;
  const int lane = tid & 63;
  const int wv   = tid >> 6;
  const int quad = lane >> 4, l15 = lane & 15;
  const int wm = wv & 1, wn = wv >> 1;
  const size_t m0 = (size_t)blockIdx.x * 64;
  const int    n0 = blockIdx.y * 64;
  const int ldr  = tid >> 2;
  const int lseg = (tid & 3) * 8;

  const u16* Ag = A + (m0 + ldr) * K + lseg;
  const u16* Wg = W + (size_t)(n0 + ldr) * K + lseg;

  f32x4 acc[2][2] = {};

#pragma unroll 1
  for (int kc = 0; kc < K; kc += 32) {
    *(short8*)&As[ldr * 40 + lseg] = *(const short8*)(Ag + kc);
    *(short8*)&Wt[ldr * 40 + lseg] = *(const short8*)(Wg + kc);
    __syncthreads();
    short8 a0 = *(const short8*)&As[(wm * 32 + l15) * 40 + quad * 8];
    short8 a1 = *(const short8*)&As[(wm * 32 + 16 + l15) * 40 + quad * 8];
    short8 b0 = *(const short8*)&Wt[(wn * 32 + l15) * 40 + quad * 8];
    short8 b1 = *(const short8*)&Wt[(wn * 32 + 16 + l15) * 40 + quad * 8];
    acc[0][0] = __builtin_amdgcn_mfma_f32_16x16x32_bf16(a0, b0, acc[0][0], 0, 0, 0);
    acc[1][0] = __builtin_amdgcn_mfma_f32_16x16x32_bf16(a1, b0, acc[1][0], 0, 0, 0);
    acc[0][1] = __builtin_amdgcn_mfma_f32_16x16x32_bf16(a0, b1, acc[0][1], 0, 0, 0);
    acc[1][1] = __builtin_amdgcn_mfma_f32_16x16x32_bf16(a1, b1, acc[1][1], 0, 0, 0);
    __syncthreads();
  }

#pragma unroll
  for (int mi = 0; mi < 2; mi++)
#pragma unroll
    for (int ni = 0; ni < 2; ni++) {
      const int nl   = wn * 32 + ni * 16 + l15;   // 0..63 within tile
      const int ncol = n0 + nl;                   // global col
      const float bv = bias[ncol];
#pragma unroll
      for (int r = 0; r < 4; r++) {
        const size_t m = m0 + wm * 32 + mi * 16 + quad * 4 + r;
        float v = acc[mi][ni][r] + bv;
        if (EPI == 0) {
          v = v > 0.0f ? v : 0.01f * v;
          ((u16*)outp)[m * (size_t)N + ncol] = f2bf(v);
        } else if (EPI == 1) {
          const int tt = (int)(m >> 8), b = (int)(m & 255);
          const int q  = ncol >> 8, jc = ncol & 255;
          const int phh = jc >> 7, jl = jc & 127;
          ((u16*)outp)[(size_t)tt * 262144 + (size_t)(q >> 1) * 131072 +
                       (size_t)b * 512 + phh * 256 + (q & 1) * 128 + jl] =
              f2bf(v);
        } else {
          if (ncol < 32)
            ((float*)outp)[m * 32 + ncol] = tanhf(v);
          else
            ((float*)outp + 4194304)[m * 32 + ncol - 32] =
                log1pf(__expf(v)) + 1e-6f;
        }
      }
    }
}

// -------------------------------------------------------------- LSTM scan
// 32 blocks = 16 groups x 2. Group g owns batches [16g,16g+16); block half
// ph owns h-dims [128ph,128ph+128) -> 512 W_hh rows register-resident as
// MFMA B-fragments (256 KB/block). Per step: full h staged in LDS (own half
// from last epilogue, partner half via exchange), 32 MFMAs/wave, fp32 gates.
//
// R4 exchange: pair = (blockIdx b, b^16) -> same XCD when dispatch is
// round-robin (b%8 == (b^16)%8). Xbuf word = bf16(h2) | ((t+1)<<16), layout
// [g][parity][jcol][m] so producer (fixed jcol, m=quad*4..+4) stores ONE
// dwordx4 and consumer (fixed jcol_p, 4 m) polls ONE dwordx4. Producer
// stores twice: plain (-> shared per-XCD L2) and sc0/sc1 (-> LLC, correct
// for any placement). Consumer alternates sc0 poll (L2 fast path) with
// sc0/sc1 poll (LLC liveness). Parity double-buffer prevents tag t+2
// clobbering unconsumed tag t (producer's t+2 write is data-dependent on
// the consumer's t+1 output).
__global__ __launch_bounds__(512, 2) void lstm_scan(
    const u16* __restrict__ Whh,    // bf16 [1024][256]
    const int* __restrict__ dones,  // [512][256]
    const u16* ig,                  // bf16, ALIASES hid region (no restrict!)
    float* hid,                     // d_out + 8388608 floats (no restrict!)
    u16* __restrict__ pre_out,      // bf16 [131072][256] = leaky_relu(h2)
    u32* __restrict__ Xbuf) {       // [16 g][2 parity][256 jcol][16 m]
  const int tid  = threadIdx.x;
  const int w    = tid >> 6;
  const int lane = tid & 63;
  const int quad = lane >> 4, l15 = lane & 15;
  // R4 pairing: (g, g+16) -> same XCD under round-robin dispatch
  const int ph = blockIdx.x >> 4, g = blockIdx.x & 15;
  const int b0 = g * 16;
  const int jl   = w * 16 + l15;    // 0..127 local h-dim
  const int jcol = ph * 128 + jl;   // global h-dim

  __shared__ __align__(16) u16 h_lds[16 * 264];  // [16 m][256 j + 8 pad]

  // --- persistent weight fragments: rows {q*256 + jcol}, q=i,f,g,o
  short8 wf[4][8];
#pragma unroll
  for (int q = 0; q < 4; q++) {
    const u16* wr = Whh + (size_t)(q * 256 + jcol) * 256;
#pragma unroll
    for (int kc = 0; kc < 8; kc++)
      wf[q][kc] = *(const short8*)(wr + kc * 32 + quad * 8);
  }

  float c4[4]   = {0.f, 0.f, 0.f, 0.f};
  float hown[4] = {0.f, 0.f, 0.f, 0.f};

  for (int i = tid; i < 16 * 264 / 2; i += 512) ((u32*)h_lds)[i] = 0;

  // receive-side addressing: thread t -> partner jcol (t&127), m = (t>>7)*4
  const int rx_j = (1 - ph) * 128 + (tid & 127);
  const int rx_m = (tid >> 7) * 4;

  // --- prefetch t=0 (dones + ig, permuted layout)
  int dpf[5];
  u16 igpf[16];
  {
    const int* dr = dones + b0;
    const int4 dv = *(const int4*)(dr + quad * 4);
    dpf[0] = dv.x; dpf[1] = dv.y; dpf[2] = dv.z; dpf[3] = dv.w;
    dpf[4] = dr[l15];
    const u16* igr = ig + (size_t)b0 * 512 + ph * 256 + jl;
#pragma unroll
    for (int q = 0; q < 4; q++)
#pragma unroll
      for (int r = 0; r < 4; r++)
        igpf[q * 4 + r] = igr[(size_t)(q >> 1) * 131072 +
                              (size_t)(quad * 4 + r) * 512 + (q & 1) * 128];
  }
  __syncthreads();   // full: drains LDS zero-init + ig[0] loads (alias safety
                     // for the t=0 hid stores below)

  const short8 z8 = {0, 0, 0, 0, 0, 0, 0, 0};

  for (int t = 0; t < 512; t++) {
    // keep masks for this step (dones prefetched last iter)
    float kc4[4];
#pragma unroll
    for (int r = 0; r < 4; r++) kc4[r] = dpf[r] ? 0.f : 1.f;
    const bool ka = (dpf[4] == 0);
    const int tn = (t < 511) ? t + 1 : 511;
    {
      const int* dr = dones + tn * 256 + b0;
      const int4 dv = *(const int4*)(dr + quad * 4);
      dpf[0] = dv.x; dpf[1] = dv.y; dpf[2] = dv.z; dpf[3] = dv.w;
      dpf[4] = dr[l15];
    }

    // --- receive partner h2 half (t>0): dwordx4 poll on tagged words.
    //     sc0 leg hits the shared per-XCD L2 (fast when pair co-resident);
    //     sc0+sc1 leg reads LLC (liveness for any placement).
    if (t > 0) {
      const u32* xs = Xbuf +
          ((((size_t)g * 2 + (t & 1)) * 256 + rx_j) * 16 + rx_m);
      const u32 want = (u32)t << 16;
      u32x4 v;
      for (;;) {
        asm volatile("global_load_dwordx4 %0, %1, off sc0\n\t"
                     "s_waitcnt vmcnt(0)"
                     : "=v"(v) : "v"(xs) : "memory");
        if ((((v[0] ^ want) | (v[1] ^ want) | (v[2] ^ want) | (v[3] ^ want))
             >> 16) == 0) break;
        asm volatile("global_load_dwordx4 %0, %1, off sc0 sc1\n\t"
                     "s_waitcnt vmcnt(0)"
                     : "=v"(v) : "v"(xs) : "memory");
        if ((((v[0] ^ want) | (v[1] ^ want) | (v[2] ^ want) | (v[3] ^ want))
             >> 16) == 0) break;
      }
#pragma unroll
      for (int i = 0; i < 4; i++)
        h_lds[(rx_m + i) * 264 + rx_j] = (u16)v[i];
    }
    // top barrier: LDS-only. vmem alias drain already done by the poll's
    // vmcnt(0) (t>0) or the pre-loop __syncthreads (t=0).
    asm volatile("s_waitcnt lgkmcnt(0)" ::: "memory");
    __builtin_amdgcn_s_barrier();
    __builtin_amdgcn_sched_barrier(0);

    // --- A fragments (h, masked by keep[l15])
    short8 af[8];
#pragma unroll
    for (int kc = 0; kc < 8; kc++)
      af[kc] = *(const short8*)&h_lds[l15 * 264 + kc * 32 + quad * 8];
    if (!ka) {
#pragma unroll
      for (int kc = 0; kc < 8; kc++) af[kc] = z8;
    }

    // mask own state (pre-step h,c after masking == hid[t])
#pragma unroll
    for (int r = 0; r < 4; r++) { c4[r] *= kc4[r]; hown[r] *= kc4[r]; }

    // acc init from prefetched ig[t]
    f32x4 acc[4];
#pragma unroll
    for (int q = 0; q < 4; q++)
#pragma unroll
      for (int r = 0; r < 4; r++) acc[q][r] = bf2f(igpf[q * 4 + r]);

    // hid[t] writes — every thread's ig[t] loads drained (see above);
    // same byte set per block, disjoint across blocks.
    {
      float* h0 = hid + ((size_t)(t * 2) * 256 + b0) * 256 + jcol;
#pragma unroll
      for (int r = 0; r < 4; r++) {
        const int m = quad * 4 + r;
        h0[(size_t)m * 256] = hown[r];
        h0[(size_t)(256 + m) * 256] = c4[r];
      }
    }

    // prefetch ig[t+1] (skip at t=511: bytes already overwritten by hid)
    if (t < 511) {
      const u16* igr = ig + (size_t)(t + 1) * 262144 + (size_t)b0 * 512 +
                       ph * 256 + jl;
#pragma unroll
      for (int q = 0; q < 4; q++)
#pragma unroll
        for (int r = 0; r < 4; r++)
          igpf[q * 4 + r] = igr[(size_t)(q >> 1) * 131072 +
                                (size_t)(quad * 4 + r) * 512 + (q & 1) * 128];
    }

    // --- gates += h @ W^T  (32 MFMAs)
#pragma unroll
    for (int kc = 0; kc < 8; kc++)
#pragma unroll
      for (int q = 0; q < 4; q++)
        acc[q] = __builtin_amdgcn_mfma_f32_16x16x32_bf16(af[kc], wf[q][kc],
                                                         acc[q], 0, 0, 0);

    // mid barrier: LDS-only (A-frag reads done before own-half overwrite);
    // hid/pre/ig vmem keeps draining in the background.
    asm volatile("s_waitcnt lgkmcnt(0)" ::: "memory");
    __builtin_amdgcn_s_barrier();
    __builtin_amdgcn_sched_barrier(0);

    // --- gate math, then PUBLISH FIRST (exchange is the critical path)
    const u32 tagw = (u32)(t + 1) << 16;
    u32x4 xw;
#pragma unroll
    for (int r = 0; r < 4; r++) {
      const float iv = acc[0][r], fv = acc[1][r], gv = acc[2][r], ov = acc[3][r];
      const float c2 = fsigmoid(fv) * c4[r] + fsigmoid(iv) * ftanh(gv);
      const float h2 = fsigmoid(ov) * ftanh(c2);
      c4[r] = c2;
      hown[r] = h2;
      xw[r] = (u32)f2bf(h2) | tagw;
    }
    {
      u32* xo = Xbuf + ((((size_t)g * 2 + ((t + 1) & 1)) * 256 + jcol) * 16 +
                        quad * 4);
      // plain -> per-XCD L2 (fast same-XCD visibility);
      // sc0 sc1 -> write-through LLC (cross-XCD correctness)
      asm volatile("global_store_dwordx4 %0, %1, off\n\t"
                   "global_store_dwordx4 %0, %1, off sc0 sc1"
                   :: "v"(xo), "v"(xw) : "memory");
    }
    u16* pr = pre_out + ((size_t)t * 256 + b0) * 256 + jcol;
#pragma unroll
    for (int r = 0; r < 4; r++) {
      const int m = quad * 4 + r;
      h_lds[m * 264 + jcol] = (u16)xw[r];                 // own half for t+1
      const float pv = hown[r] > 0.0f ? hown[r] : 0.01f * hown[r];
      pr[(size_t)m * 256] = f2bf(pv);                     // pre = lrelu(h2)
    }
    // no trailing barrier: next step's top barrier orders LDS, and the
    // tag-in-word protocol needs no store drain before a flag.
  }
}

// ---------------------------------------------------------------------------
extern "C" void kernel_launch(void* const* d_in, const int* in_sizes, int n_in,
                              void* d_out, int out_size, void* d_ws, size_t ws_size,
                              hipStream_t stream) {
  const float* x    = (const float*)d_in[0];
  const int*   dns  = (const int*)d_in[1];
  const float* W1   = (const float*)d_in[2];
  const float* b1   = (const float*)d_in[3];
  const float* Wih  = (const float*)d_in[4];
  const float* Whh  = (const float*)d_in[5];
  const float* bih  = (const float*)d_in[6];
  const float* bhh  = (const float*)d_in[7];
  const float* Wm   = (const float*)d_in[8];
  const float* bm   = (const float*)d_in[9];
  const float* Wsd  = (const float*)d_in[10];
  const float* bs   = (const float*)d_in[11];

  char* ws = (char*)d_ws;
  u16*   shb  = (u16*)(ws + OFF_SH);
  u16*   preb = (u16*)(ws + OFF_PRE);
  u16*   W1b  = (u16*)(ws + OFF_W1);
  u16*   Wihb = (u16*)(ws + OFF_WIH);
  u16*   Whhb = (u16*)(ws + OFF_WHH);
  u16*   Wcb  = (u16*)(ws + OFF_WCAT);
  float* bigv = (float*)(ws + OFF_BIG);
  float* bct  = (float*)(ws + OFF_BCAT);
  u32*   Xb   = (u32*)(ws + OFF_X);

  u16*   xb  = (u16*)d_out;                          // aliases means+stds
  u16*   igb = (u16*)((char*)d_out + 33554432);      // aliases hidden_outputs
  float* hid = (float*)d_out + 8388608;

  k_conv_x<<<512, 256, 0, stream>>>(x, xb);
  k_small<<<64, 256, 0, stream>>>(W1, Wih, Whh, Wm, Wsd, bih, bhh, bm, bs,
                                  W1b, Wihb, Whhb, Wcb, bigv, bct);
  gemm_bt<128, 0><<<dim3(2048, 4), 256, 0, stream>>>(xb, W1b, b1, shb, 256);
  gemm_bt<256, 1><<<dim3(2048, 16), 256, 0, stream>>>(shb, Wihb, bigv, igb, 1024);
  lstm_scan<<<32, 512, 0, stream>>>(Whhb, dns, igb, hid, preb, Xb);
  gemm_bt<256, 2><<<dim3(2048, 1), 256, 0, stream>>>(preb, Wcb, bct, d_out, 64);
}

// Round 3
// 2508.328 us; speedup vs baseline: 1.0585x; 1.0136x over previous
//
#include <hip/hip_runtime.h>

// ---------------------------------------------------------------------------
// GaussianGradientLSTMPolicy on MI355X
//   A0: fp32 -> bf16 converts (x, weights), bias fusions
//   A2: shared = leaky_relu(x @ W1^T + b1)                  [131072 x 256]
//   A3: ig     = shared @ W_ih^T + (b_ih + b_hh)  (permuted)[131072 x 1024]
//   B : persistent-register LSTM scan, block pairs exchange h halves
//       R6: runtime XCD discovery pairing + ALWAYS-live dual-path exchange
//         - registration: each block reads XCC_ID (hwreg 20), publishes
//           (xcd, rank) -> blockIdx in a ctl table (release/acquire on an
//           arrival counter). Pairs are formed WITHIN each XCD's list;
//           leftovers from odd-count XCDs are pooled deterministically.
//         - exchange protocol (placement-independent, R4-proven live):
//           producer ALWAYS dual-stores (plain -> local L2, sc0 sc1 -> LLC);
//           consumer ALWAYS alternates sc0 poll / sc0+sc1 poll. Same-XCD
//           pairs rendezvous in their shared L2 via the plain store + sc0
//           poll; cross-XCD pairs fall back to the LLC legs. No modes, no
//           timeouts -> no deadlock for ANY placement.
//         - dones preloaded to LDS (packed bytes): no cold HBM load inside
//           the poll's vmcnt(0) drain.
//         - h_lds parity double-buffer: ONE lgkm-only barrier per step.
//         - hid[t] stores delayed to step t+1: alias safety because every
//           thread's ig[t] loads are drained by its own poll[t] vmcnt(0)
//           (t=0: pre-loop __syncthreads) and barrier[t] precedes the step
//           t+1 stores.
//   C : means = tanh(pre@Wm^T+bm), stds = softplus(pre@Ws^T+bs)+eps
// Aliasing:
//   - x_bf16 lives in d_out[0 .. 32MiB) (means+stds region), consumed by A2
//   - ctl (pairing table) lives in the LAST 2KB of that region: dead after
//     A2 reads x_bf16, zeroed by k_zero_ctl (after A2), used by the scan,
//     overwritten by the heads GEMM (stds) afterwards.
//   - ig (bf16) lives in the d_out hidden_outputs region with a PERMUTED
//     layout such that the bytes block (g,ph) reads as ig[t] are exactly the
//     bytes it writes as hid[t]:
//       idx_u16(t,b,q,ph,jl) = t*262144 + (q>>1)*131072 + b*512
//                              + ph*256 + (q&1)*128 + jl
// ---------------------------------------------------------------------------

typedef __attribute__((ext_vector_type(8))) short short8;
typedef __attribute__((ext_vector_type(4))) float f32x4;
typedef __attribute__((ext_vector_type(4))) unsigned short u16x4;
typedef __attribute__((ext_vector_type(4))) unsigned int u32x4;
typedef unsigned short u16;
typedef unsigned int   u32;

// ws layout (bytes)
constexpr size_t OFF_SH   = 0;                      // shared bf16   67108864
constexpr size_t OFF_PRE  = 67108864;               // pre bf16      67108864
constexpr size_t OFF_W1   = 134217728;              // W1 bf16          65536
constexpr size_t OFF_WIH  = OFF_W1   + 65536;       // W_ih bf16       524288
constexpr size_t OFF_WHH  = OFF_WIH  + 524288;      // W_hh bf16       524288
constexpr size_t OFF_WCAT = OFF_WHH  + 524288;      // [Wm;Ws] bf16     32768
constexpr size_t OFF_BIG  = OFF_WCAT + 32768;       // b_ih+b_hh f32     4096
constexpr size_t OFF_BCAT = OFF_BIG  + 4096;        // [bm;bs] f32        256
constexpr size_t OFF_X    = OFF_BCAT + 256;         // h2 exchange     524288
// total ~136 MB

__device__ __forceinline__ u16 f2bf(float f) {
  union { float f; u32 u; } v; v.f = f;
  u32 u = v.u;
  return (u16)((u + 0x7fffu + ((u >> 16) & 1u)) >> 16);   // RNE
}
__device__ __forceinline__ float bf2f(u16 h) {
  union { u32 u; float f; } v; v.u = ((u32)h) << 16; return v.f;
}
__device__ __forceinline__ float fsigmoid(float x) {
  return 1.0f / (1.0f + __expf(-x));
}
__device__ __forceinline__ float ftanh(float x) {
  return 1.0f - 2.0f / (__expf(2.0f * x) + 1.0f);
}

// ---------------------------------------------------------------- converts
__global__ void k_conv_x(const float* __restrict__ x, u16* __restrict__ o) {
  const size_t stride = (size_t)gridDim.x * blockDim.x;
  for (size_t i = (size_t)blockIdx.x * blockDim.x + threadIdx.x;
       i < 16777216 / 4; i += stride) {
    f32x4 v = ((const f32x4*)x)[i];
    u16x4 r;
    r[0] = f2bf(v[0]); r[1] = f2bf(v[1]); r[2] = f2bf(v[2]); r[3] = f2bf(v[3]);
    ((u16x4*)o)[i] = r;
  }
}

__global__ void k_small(const float* __restrict__ W1, const float* __restrict__ Wih,
                        const float* __restrict__ Whh, const float* __restrict__ Wm,
                        const float* __restrict__ Ws,  const float* __restrict__ bih,
                        const float* __restrict__ bhh, const float* __restrict__ bm,
                        const float* __restrict__ bs,
                        u16* __restrict__ W1b, u16* __restrict__ Wihb,
                        u16* __restrict__ Whhb, u16* __restrict__ Wcatb,
                        float* __restrict__ bigv, float* __restrict__ bcatv) {
  const int stride = gridDim.x * blockDim.x;
  const int i0 = blockIdx.x * blockDim.x + threadIdx.x;
  for (int i = i0; i < 32768;  i += stride) W1b[i]  = f2bf(W1[i]);
  for (int i = i0; i < 262144; i += stride) Wihb[i] = f2bf(Wih[i]);
  for (int i = i0; i < 262144; i += stride) Whhb[i] = f2bf(Whh[i]);
  for (int i = i0; i < 8192;   i += stride) Wcatb[i]        = f2bf(Wm[i]);
  for (int i = i0; i < 8192;   i += stride) Wcatb[8192 + i] = f2bf(Ws[i]);
  for (int i = i0; i < 1024;   i += stride) bigv[i] = bih[i] + bhh[i];
  for (int i = i0; i < 32;     i += stride) bcatv[i]      = bm[i];
  for (int i = i0; i < 32;     i += stride) bcatv[32 + i] = bs[i];
}

// zero the pairing/control area (system scope -> LLC is the point of truth)
__global__ void k_zero_ctl(u32* __restrict__ ctl) {
  if (threadIdx.x < 512)
    __hip_atomic_store(&ctl[threadIdx.x], 0u, __ATOMIC_RELAXED,
                       __HIP_MEMORY_SCOPE_SYSTEM);
}

// ------------------------------------------------------------ generic GEMM
// C[M,N] = epi(A[M,K] @ W[N,K]^T + bias), bf16 in, fp32 acc.
// EPI 0: leaky_relu -> bf16 out (ld = N)
// EPI 1: bf16 out, permuted so scan-block (g,ph)'s ig[t] bytes == its hid[t]
// EPI 2: heads: n<32 -> tanh -> means(f32); n>=32 -> softplus+eps -> stds
template <int K, int EPI>
__global__ __launch_bounds__(256) void gemm_bt(const u16* __restrict__ A,
                                               const u16* __restrict__ W,
                                               const float* __restrict__ bias,
                                               void* __restrict__ outp, int N) {
  __shared__ __align__(16) u16 As[64 * 40];   // +8 pad: 2-way banks only
  __shared__ __align__(16) u16 Wt[64 * 40];
  const int tid  = threadIdx.x;
  const int lane = tid & 63;
  const int wv   = tid >> 6;
  const int quad = lane >> 4, l15 = lane & 15;
  const int wm = wv & 1, wn = wv >> 1;
  const size_t m0 = (size_t)blockIdx.x * 64;
  const int    n0 = blockIdx.y * 64;
  const int ldr  = tid >> 2;
  const int lseg = (tid & 3) * 8;

  const u16* Ag = A + (m0 + ldr) * K + lseg;
  const u16* Wg = W + (size_t)(n0 + ldr) * K + lseg;

  f32x4 acc[2][2] = {};

#pragma unroll 1
  for (int kc = 0; kc < K; kc += 32) {
    *(short8*)&As[ldr * 40 + lseg] = *(const short8*)(Ag + kc);
    *(short8*)&Wt[ldr * 40 + lseg] = *(const short8*)(Wg + kc);
    __syncthreads();
    short8 a0 = *(const short8*)&As[(wm * 32 + l15) * 40 + quad * 8];
    short8 a1 = *(const short8*)&As[(wm * 32 + 16 + l15) * 40 + quad * 8];
    short8 b0 = *(const short8*)&Wt[(wn * 32 + l15) * 40 + quad * 8];
    short8 b1 = *(const short8*)&Wt[(wn * 32 + 16 + l15) * 40 + quad * 8];
    acc[0][0] = __builtin_amdgcn_mfma_f32_16x16x32_bf16(a0, b0, acc[0][0], 0, 0, 0);
    acc[1][0] = __builtin_amdgcn_mfma_f32_16x16x32_bf16(a1, b0, acc[1][0], 0, 0, 0);
    acc[0][1] = __builtin_amdgcn_mfma_f32_16x16x32_bf16(a0, b1, acc[0][1], 0, 0, 0);
    acc[1][1] = __builtin_amdgcn_mfma_f32_16x16x32_bf16(a1, b1, acc[1][1], 0, 0, 0);
    __syncthreads();
  }

#pragma unroll
  for (int mi = 0; mi < 2; mi++)
#pragma unroll
    for (int ni = 0; ni < 2; ni++) {
      const int nl   = wn * 32 + ni * 16 + l15;   // 0..63 within tile
      const int ncol = n0 + nl;                   // global col
      const float bv = bias[ncol];
#pragma unroll
      for (int r = 0; r < 4; r++) {
        const size_t m = m0 + wm * 32 + mi * 16 + quad * 4 + r;
        float v = acc[mi][ni][r] + bv;
        if (EPI == 0) {
          v = v > 0.0f ? v : 0.01f * v;
          ((u16*)outp)[m * (size_t)N + ncol] = f2bf(v);
        } else if (EPI == 1) {
          const int tt = (int)(m >> 8), b = (int)(m & 255);
          const int q  = ncol >> 8, jc = ncol & 255;
          const int phh = jc >> 7, jl = jc & 127;
          ((u16*)outp)[(size_t)tt * 262144 + (size_t)(q >> 1) * 131072 +
                       (size_t)b * 512 + phh * 256 + (q & 1) * 128 + jl] =
              f2bf(v);
        } else {
          if (ncol < 32)
            ((float*)outp)[m * 32 + ncol] = tanhf(v);
          else
            ((float*)outp + 4194304)[m * 32 + ncol - 32] =
                log1pf(__expf(v)) + 1e-6f;
        }
      }
    }
}

// -------------------------------------------------------------- LSTM scan
// 32 blocks = 16 pairs x 2, pairs formed by runtime XCD discovery (same-XCD
// preferred). Pair p owns batches [16p,16p+16); half ph owns h-dims
// [128ph,128ph+128) -> 512 W_hh rows register-resident as MFMA B-frags.
// Xbuf word = bf16(h2) | ((t+1)<<16), layout [pair][parity][jcol][m]:
// publish and poll are each one dwordx4. Parity double-buffer prevents tag
// t+2 clobbering unconsumed tag t.
__global__ __launch_bounds__(512, 2) void lstm_scan(
    const u16* __restrict__ Whh,    // bf16 [1024][256]
    const int* __restrict__ dones,  // [512][256]
    const u16* ig,                  // bf16, ALIASES hid region (no restrict!)
    float* hid,                     // d_out + 8388608 floats (no restrict!)
    u16* __restrict__ pre_out,      // bf16 [131072][256] = leaky_relu(h2)
    u32* __restrict__ Xbuf,         // [16 pair][2 parity][256 jcol][16 m]
    u32* __restrict__ ctl) {        // [0..7]=cnt [8]=arrivals [16+x*32+r]=bid+1
  const int tid  = threadIdx.x;
  const int w    = tid >> 6;
  const int lane = tid & 63;
  const int quad = lane >> 4, l15 = lane & 15;

  __shared__ int s_pair[2];
  __shared__ __align__(16) u16 h_lds[2][16 * 264];  // parity dbuf
  __shared__ u32 dns_lds[512 * 4];  // [t][qw]: 4 batches/word, 1 byte each

  // ---- registration: discover XCC, build pairing (tid 0 only) ------------
  if (tid == 0) {
    u32 xcc;
    asm volatile("s_getreg_b32 %0, hwreg(20, 0, 32)" : "=s"(xcc));  // XCC_ID
    xcc &= 7u;
    u32 rank = __hip_atomic_fetch_add(&ctl[xcc], 1u, __ATOMIC_RELAXED,
                                      __HIP_MEMORY_SCOPE_SYSTEM);
    if (rank < 32u)
      __hip_atomic_store(&ctl[16 + xcc * 32 + rank], blockIdx.x + 1u,
                         __ATOMIC_RELAXED, __HIP_MEMORY_SCOPE_SYSTEM);
    __hip_atomic_fetch_add(&ctl[8], 1u, __ATOMIC_RELEASE,
                           __HIP_MEMORY_SCOPE_SYSTEM);
    while (__hip_atomic_load(&ctl[8], __ATOMIC_ACQUIRE,
                             __HIP_MEMORY_SCOPE_SYSTEM) < 32u) {}
    // deterministic pairing: same-XCD pairs first, then pooled leftovers
    const u32 me = blockIdx.x + 1u;
    int pid = 0, half = 0, np = 0;
    u32 leftover[8]; int nl = 0;
    for (int xx = 0; xx < 8; xx++) {
      u32 c = __hip_atomic_load(&ctl[xx], __ATOMIC_RELAXED,
                                __HIP_MEMORY_SCOPE_SYSTEM);
      if (c > 32u) c = 32u;
      const u32 ce = c & ~1u;
      for (u32 r = 0; r < ce; r += 2) {
        u32 bA, bB;
        do { bA = __hip_atomic_load(&ctl[16 + xx * 32 + r], __ATOMIC_RELAXED,
                                    __HIP_MEMORY_SCOPE_SYSTEM); } while (!bA);
        do { bB = __hip_atomic_load(&ctl[16 + xx * 32 + r + 1], __ATOMIC_RELAXED,
                                    __HIP_MEMORY_SCOPE_SYSTEM); } while (!bB);
        if (bA == me) { pid = np; half = 0; }
        if (bB == me) { pid = np; half = 1; }
        np++;
      }
      if (c & 1u) {
        u32 bL;
        do { bL = __hip_atomic_load(&ctl[16 + xx * 32 + c - 1], __ATOMIC_RELAXED,
                                    __HIP_MEMORY_SCOPE_SYSTEM); } while (!bL);
        leftover[nl++] = bL;
      }
    }
    for (int k = 0; k + 1 < nl; k += 2) {
      if (leftover[k] == me)     { pid = np; half = 0; }
      if (leftover[k + 1] == me) { pid = np; half = 1; }
      np++;
    }
    s_pair[0] = pid;
    s_pair[1] = half;
  }
  __syncthreads();

  const int g  = s_pair[0];
  const int ph = s_pair[1];
  const int b0 = g * 16;
  const int jl   = w * 16 + l15;    // 0..127 local h-dim
  const int jcol = ph * 128 + jl;   // global h-dim

  // receive-side addressing: thread -> partner jcol (tid&127), m=(tid>>7)*4
  const int rx_j = (1 - ph) * 128 + (tid & 127);
  const int rx_m = (tid >> 7) * 4;

  // ---- persistent weight fragments: rows {q*256 + jcol}, q=i,f,g,o
  short8 wf[4][8];
#pragma unroll
  for (int q = 0; q < 4; q++) {
    const u16* wr = Whh + (size_t)(q * 256 + jcol) * 256;
#pragma unroll
    for (int kc = 0; kc < 8; kc++)
      wf[q][kc] = *(const short8*)(wr + kc * 32 + quad * 8);
  }

  // ---- dones -> LDS, packed 4 batches/word
  for (int i = tid; i < 2048; i += 512) {
    const int t = i >> 2, qw = i & 3;
    const int4 dv = *(const int4*)(dones + (size_t)t * 256 + b0 + qw * 4);
    dns_lds[i] = (u32)dv.x | ((u32)dv.y << 8) | ((u32)dv.z << 16) |
                 ((u32)dv.w << 24);
  }

  // ---- zero h buffer 0 (t=0 state is all-zero)
  for (int i = tid; i < 16 * 264 / 2; i += 512) ((u32*)h_lds[0])[i] = 0;

  // ---- prefetch ig[0] (permuted layout)
  u16 igpf[16];
  {
    const u16* igr = ig + (size_t)b0 * 512 + ph * 256 + jl;
#pragma unroll
    for (int q = 0; q < 4; q++)
#pragma unroll
      for (int r = 0; r < 4; r++)
        igpf[q * 4 + r] = igr[(size_t)(q >> 1) * 131072 +
                              (size_t)(quad * 4 + r) * 512 + (q & 1) * 128];
  }
  __syncthreads();   // full barrier: drains LDS init + ig[0] loads
                     // (alias safety baseline for the delayed hid stores)

  const short8 z8 = {0, 0, 0, 0, 0, 0, 0, 0};
  float c4[4]    = {0.f, 0.f, 0.f, 0.f};
  float hown[4]  = {0.f, 0.f, 0.f, 0.f};
  float hprev[4] = {0.f, 0.f, 0.f, 0.f};
  float cprev[4] = {0.f, 0.f, 0.f, 0.f};

  for (int t = 0; t < 512; t++) {
    // dones masks for this step (LDS)
    const u32 dwk = dns_lds[t * 4 + quad];
    const u32 dwa = dns_lds[t * 4 + (l15 >> 2)];

    // --- receive partner h2 half (t>0): dwordx4 tag poll ------------------
    if (t > 0) {
      const u32* xs = Xbuf +
          ((((size_t)g * 2 + (t & 1)) * 256 + rx_j) * 16 + rx_m);
      const u32 want = (u32)t << 16;
      u32x4 v;
      for (;;) {
        asm volatile("global_load_dwordx4 %0, %1, off sc0\n\t"
                     "s_waitcnt vmcnt(0)"
                     : "=v"(v) : "v"(xs) : "memory");
        if ((((v[0] ^ want) | (v[1] ^ want) | (v[2] ^ want) |
              (v[3] ^ want)) >> 16) == 0) break;
        asm volatile("global_load_dwordx4 %0, %1, off sc0 sc1\n\t"
                     "s_waitcnt vmcnt(0)"
                     : "=v"(v) : "v"(xs) : "memory");
        if ((((v[0] ^ want) | (v[1] ^ want) | (v[2] ^ want) |
              (v[3] ^ want)) >> 16) == 0) break;
      }
#pragma unroll
      for (int i = 0; i < 4; i++)
        h_lds[t & 1][(rx_m + i) * 264 + rx_j] = (u16)v[i];

      // delayed hid[t-1] stores: every thread's ig[t-1] loads were drained
      // by its own poll[t-1] vmcnt(0) (t=1: pre-loop __syncthreads), and
      // barrier[t-1] precedes these stores.
      float* h0 = hid + ((size_t)((t - 1) * 2) * 256 + b0) * 256 + jcol;
#pragma unroll
      for (int r = 0; r < 4; r++) {
        const int m = quad * 4 + r;
        h0[(size_t)m * 256] = hprev[r];
        h0[(size_t)(256 + m) * 256] = cprev[r];
      }
    }

    // one lgkm-only barrier per step: orders receive-writes (t&1 buffer)
    // and last step's own-half writes before the af reads below.
    asm volatile("s_waitcnt lgkmcnt(0)" ::: "memory");
    __builtin_amdgcn_s_barrier();
    __builtin_amdgcn_sched_barrier(0);

    // --- A fragments (h, masked by keep[l15])
    short8 af[8];
#pragma unroll
    for (int kc = 0; kc < 8; kc++)
      af[kc] = *(const short8*)&h_lds[t & 1][l15 * 264 + kc * 32 + quad * 8];
    const bool ka = ((dwa >> ((l15 & 3) * 8)) & 0xffu) == 0u;
    if (!ka) {
#pragma unroll
      for (int kc = 0; kc < 8; kc++) af[kc] = z8;
    }

    // mask own state; save (== hid[t]) for the delayed store next step
#pragma unroll
    for (int r = 0; r < 4; r++) {
      const float kv = ((dwk >> (8 * r)) & 0xffu) ? 0.f : 1.f;
      c4[r] *= kv; hown[r] *= kv;
      hprev[r] = hown[r]; cprev[r] = c4[r];
    }

    // acc init from prefetched ig[t]
    f32x4 acc[4];
#pragma unroll
    for (int q = 0; q < 4; q++)
#pragma unroll
      for (int r = 0; r < 4; r++) acc[q][r] = bf2f(igpf[q * 4 + r]);

    // prefetch ig[t+1] (bytes overwritten only by hid[t+1] at step t+2)
    if (t < 511) {
      const u16* igr = ig + (size_t)(t + 1) * 262144 + (size_t)b0 * 512 +
                       ph * 256 + jl;
#pragma unroll
      for (int q = 0; q < 4; q++)
#pragma unroll
        for (int r = 0; r < 4; r++)
          igpf[q * 4 + r] = igr[(size_t)(q >> 1) * 131072 +
                                (size_t)(quad * 4 + r) * 512 + (q & 1) * 128];
    }

    // --- gates += h @ W^T  (32 MFMAs, 4 independent chains)
#pragma unroll
    for (int kc = 0; kc < 8; kc++)
#pragma unroll
      for (int q = 0; q < 4; q++)
        acc[q] = __builtin_amdgcn_mfma_f32_16x16x32_bf16(af[kc], wf[q][kc],
                                                         acc[q], 0, 0, 0);

    // --- gate math, then PUBLISH FIRST (exchange is the critical path)
    const u32 tagw = (u32)(t + 1) << 16;
    u32x4 xw;
#pragma unroll
    for (int r = 0; r < 4; r++) {
      const float iv = acc[0][r], fv = acc[1][r], gv = acc[2][r], ov = acc[3][r];
      const float c2 = fsigmoid(fv) * c4[r] + fsigmoid(iv) * ftanh(gv);
      const float h2 = fsigmoid(ov) * ftanh(c2);
      c4[r] = c2;
      hown[r] = h2;
      xw[r] = (u32)f2bf(h2) | tagw;
    }
    {
      u32* xo = Xbuf + ((((size_t)g * 2 + ((t + 1) & 1)) * 256 + jcol) * 16 +
                        quad * 4);
      // plain -> local L2 (fast same-XCD rendezvous);
      // sc0 sc1 -> write-through LLC (liveness for any placement)
      asm volatile("global_store_dwordx4 %0, %1, off\n\t"
                   "global_store_dwordx4 %0, %1, off sc0 sc1"
                   :: "v"(xo), "v"(xw) : "memory");
    }
    u16* pr = pre_out + ((size_t)t * 256 + b0) * 256 + jcol;
#pragma unroll
    for (int r = 0; r < 4; r++) {
      const int m = quad * 4 + r;
      h_lds[(t + 1) & 1][m * 264 + jcol] = (u16)xw[r];  // own half for t+1
      const float pv = hown[r] > 0.0f ? hown[r] : 0.01f * hown[r];
      pr[(size_t)m * 256] = f2bf(pv);                   // pre = lrelu(h2)
    }
    // no trailing barrier: next step's barrier orders LDS; tag protocol
    // needs no store drain before a flag (tag is in the data word).
  }

  // flush hid[511]; barrier first so every wave's ig[511] loads (drained at
  // its poll[511]) are complete before the bytes are overwritten.
  __syncthreads();
  {
    float* h0 = hid + ((size_t)(511 * 2) * 256 + b0) * 256 + jcol;
#pragma unroll
    for (int r = 0; r < 4; r++) {
      const int m = quad * 4 + r;
      h0[(size_t)m * 256] = hprev[r];
      h0[(size_t)(256 + m) * 256] = cprev[r];
    }
  }
}

// ---------------------------------------------------------------------------
extern "C" void kernel_launch(void* const* d_in, const int* in_sizes, int n_in,
                              void* d_out, int out_size, void* d_ws, size_t ws_size,
                              hipStream_t stream) {
  const float* x    = (const float*)d_in[0];
  const int*   dns  = (const int*)d_in[1];
  const float* W1   = (const float*)d_in[2];
  const float* b1   = (const float*)d_in[3];
  const float* Wih  = (const float*)d_in[4];
  const float* Whh  = (const float*)d_in[5];
  const float* bih  = (const float*)d_in[6];
  const float* bhh  = (const float*)d_in[7];
  const float* Wm   = (const float*)d_in[8];
  const float* bm   = (const float*)d_in[9];
  const float* Wsd  = (const float*)d_in[10];
  const float* bs   = (const float*)d_in[11];

  char* ws = (char*)d_ws;
  u16*   shb  = (u16*)(ws + OFF_SH);
  u16*   preb = (u16*)(ws + OFF_PRE);
  u16*   W1b  = (u16*)(ws + OFF_W1);
  u16*   Wihb = (u16*)(ws + OFF_WIH);
  u16*   Whhb = (u16*)(ws + OFF_WHH);
  u16*   Wcb  = (u16*)(ws + OFF_WCAT);
  float* bigv = (float*)(ws + OFF_BIG);
  float* bct  = (float*)(ws + OFF_BCAT);
  u32*   Xb   = (u32*)(ws + OFF_X);

  u16*   xb  = (u16*)d_out;                          // aliases means+stds
  u16*   igb = (u16*)((char*)d_out + 33554432);      // aliases hidden_outputs
  float* hid = (float*)d_out + 8388608;
  // ctl: last 2KB of the means+stds region — dead between A2 and the heads
  u32*   ctl = (u32*)((char*)d_out + 33554432 - 2048);

  k_conv_x<<<512, 256, 0, stream>>>(x, xb);
  k_small<<<64, 256, 0, stream>>>(W1, Wih, Whh, Wm, Wsd, bih, bhh, bm, bs,
                                  W1b, Wihb, Whhb, Wcb, bigv, bct);
  gemm_bt<128, 0><<<dim3(2048, 4), 256, 0, stream>>>(xb, W1b, b1, shb, 256);
  k_zero_ctl<<<1, 512, 0, stream>>>(ctl);
  gemm_bt<256, 1><<<dim3(2048, 16), 256, 0, stream>>>(shb, Wihb, bigv, igb, 1024);
  lstm_scan<<<32, 512, 0, stream>>>(Whhb, dns, igb, hid, preb, Xb, ctl);
  gemm_bt<256, 2><<<dim3(2048, 1), 256, 0, stream>>>(preb, Wcb, bct, d_out, 64);
}